// Round 10
// baseline (170.139 us; speedup 1.0000x reference)
//
#include <hip/hip_runtime.h>
#include <math.h>

#define BB 4096
#define FF 64
#define RR 16   // F / RED
#define DD 512
#define KK 8

typedef float f32x4 __attribute__((ext_vector_type(4)));

// One block per batch. 512 threads (8 waves), 128 KiB dynamic LDS stages the
// block's entire x-slice so the top-k gather never re-touches HBM/L2.
// 1 block/CU (LDS-capped) -> 16 sequential generations of 4096 blocks.
__global__ __launch_bounds__(512) void ca1d_fused(
    const float* __restrict__ x,   // [B,F,D]
    const float* __restrict__ w1,  // [R,F]
    const float* __restrict__ b1,  // [R]
    const float* __restrict__ w2,  // [F,R]
    const float* __restrict__ b2,  // [F]
    float* __restrict__ out)       // [B,K,D]
{
    extern __shared__ float s_x[];        // [FF * DD] = 128 KiB staging
    __shared__ double s_pooled[FF];
    __shared__ double s_h[RR];
    __shared__ double s_z[FF];
    __shared__ float  s_w[FF];
    __shared__ int    s_idx[KK];

    const int b    = blockIdx.x;
    const int tid  = threadIdx.x;
    const int lane = tid & 63;
    const int wave = tid >> 6;   // 0..7

    const float* xb = x + (size_t)b * FF * DD;

    // ---- Stage 1: pooled[f] = mean_D x[b,f,:]  (BIT-FROZEN reduce order:
    // per-lane pair tree, then xor 32,16,8,4,2,1, *1/512 by lane 0).
    // Each row is also staged to LDS (same register bits, fire-and-forget).
    // Loads are nontemporal: nothing ever re-reads x from global.
    #pragma unroll 4
    for (int i = 0; i < FF / 8; ++i) {
        const int f = wave + (i << 3);
        const f32x4* row = (const f32x4*)(xb + f * DD);
        f32x4 v0 = __builtin_nontemporal_load(row + lane);       // coalesced 1 KiB/instr
        f32x4 v1 = __builtin_nontemporal_load(row + lane + 64);
        f32x4* dst = (f32x4*)(s_x + f * DD);
        dst[lane]      = v0;   // ds_write_b128, 2-way bank alias = free
        dst[lane + 64] = v1;
        double s = ((double)v0[0] + (double)v0[1]) + ((double)v0[2] + (double)v0[3])
                 + ((double)v1[0] + (double)v1[1]) + ((double)v1[2] + (double)v1[3]);
        #pragma unroll
        for (int off = 32; off > 0; off >>= 1)
            s += __shfl_xor(s, off, 64);
        if (lane == 0) s_pooled[f] = s * (1.0 / DD);
    }
    __syncthreads();

    // ---- Stage 2: h[r] = relu(dot(pooled, w1[r,:]) + b1[r])   (f64 exact, BIT-FROZEN)
    if (tid < RR) {
        double acc = (double)b1[tid];
        const float* wr = w1 + tid * FF;
        #pragma unroll
        for (int f = 0; f < FF; ++f) acc += s_pooled[f] * (double)wr[f];
        s_h[tid] = acc > 0.0 ? acc : 0.0;
    }
    __syncthreads();

    // ---- Stage 3: z[f] = dot(h, w2[f,:]) + b2[f]   (f64 exact, BIT-FROZEN)
    if (tid < FF) {
        double acc = (double)b2[tid];
        const float* wf = w2 + tid * RR;
        #pragma unroll
        for (int r = 0; r < RR; ++r) acc += s_h[r] * (double)wf[r];
        s_z[tid] = acc;
    }
    __syncthreads();

    // ---- Stage 4: top-K on the np-style THREE-ROUNDING sigmoid chain
    // (BIT-FROZEN):  e = f32(exp(-z)); den = f32(1+e); w = f32(1/den).
    // Rank-based selection == descending w, exact ties -> lower index.
    if (wave == 0) {
        float e   = (float)exp(-s_z[lane]);   // f64 exp -> f32 round
        float den = 1.0f + e;                 // f32 round
        float v   = 1.0f / den;               // f32 round
        s_w[lane] = v;
        int rank = 0;
        #pragma unroll
        for (int j = 0; j < FF; ++j) {
            float wj = s_w[j];                // uniform broadcast, conflict-free
            rank += (wj > v || (wj == v && j < lane)) ? 1 : 0;
        }
        if (rank < KK) s_idx[rank] = lane;
    }
    __syncthreads();

    // ---- Stage 5: gather 8 selected rows from LDS -> out[b, k, :]
    // (zero global re-read; nontemporal stores keep L2 clean)
    f32x4* ob = (f32x4*)(out + (size_t)b * KK * DD);
    #pragma unroll
    for (int i = tid; i < KK * DD / 4; i += 512) {   // 1024 float4, 2 per thread
        int k = i >> 7;        // / 128
        int c = i & 127;
        const f32x4* src = (const f32x4*)(s_x + (size_t)s_idx[k] * DD);
        __builtin_nontemporal_store(src[c], ob + i);
    }
}

extern "C" void kernel_launch(void* const* d_in, const int* in_sizes, int n_in,
                              void* d_out, int out_size, void* d_ws, size_t ws_size,
                              hipStream_t stream) {
    const float* x  = (const float*)d_in[0];
    const float* w1 = (const float*)d_in[1];
    const float* b1 = (const float*)d_in[2];
    const float* w2 = (const float*)d_in[3];
    const float* b2 = (const float*)d_in[4];
    float* out = (float*)d_out;

    ca1d_fused<<<BB, 512, FF * DD * sizeof(float), stream>>>(x, w1, b1, w2, b2, out);
}

// Round 11
// 129.549 us; speedup vs baseline: 1.3133x; 1.3133x over previous
//
#include <hip/hip_runtime.h>
#include <math.h>

#define BB 4096
#define FF 64
#define RR 16   // F / RED
#define DD 512
#define KK 8

typedef float f32x4 __attribute__((ext_vector_type(4)));

// One block per batch, 256 threads (4 waves). Wave w owns rows {w, w+4, ...,
// w+60}; each thread keeps its 32 loaded f32x4 (128 VGPRs) live so the
// selected rows are stored straight from registers: zero gather re-read,
// no 128KiB-LDS occupancy collapse (R10 lesson). 2 blocks/CU.
__global__ __launch_bounds__(256, 2) void ca1d_fused(
    const float* __restrict__ x,   // [B,F,D]
    const float* __restrict__ w1,  // [R,F]
    const float* __restrict__ b1,  // [R]
    const float* __restrict__ w2,  // [F,R]
    const float* __restrict__ b2,  // [F]
    float* __restrict__ out)       // [B,K,D]
{
    __shared__ double s_pooled[FF];
    __shared__ double s_h[RR];
    __shared__ double s_z[FF];
    __shared__ float  s_w[FF];
    __shared__ int    s_rank[FF];

    const int b    = blockIdx.x;
    const int tid  = threadIdx.x;
    const int lane = tid & 63;
    const int wave = tid >> 6;   // 0..3

    const float* xb = x + (size_t)b * FF * DD;

    // ---- Stage 1a: load rows into registers (nontemporal: never re-read).
    // 32 independent loads/thread -> deep VMEM queue, no chain stalls.
    f32x4 v0[16], v1[16];
    #pragma unroll
    for (int i = 0; i < 16; ++i) {
        const int f = wave + (i << 2);
        const f32x4* row = (const f32x4*)(xb + f * DD);
        v0[i] = __builtin_nontemporal_load(row + lane);        // floats 4L..4L+3
        v1[i] = __builtin_nontemporal_load(row + lane + 64);   // floats 256+4L..
    }

    // ---- Stage 1b: pooled[f] = mean (BIT-FROZEN order: per-lane pair tree,
    // xor-shuffle 32,16,8,4,2,1, *1/512 by lane 0 — identical to R8/R9).
    #pragma unroll
    for (int i = 0; i < 16; ++i) {
        const int f = wave + (i << 2);
        double s = ((double)v0[i][0] + (double)v0[i][1]) + ((double)v0[i][2] + (double)v0[i][3])
                 + ((double)v1[i][0] + (double)v1[i][1]) + ((double)v1[i][2] + (double)v1[i][3]);
        #pragma unroll
        for (int off = 32; off > 0; off >>= 1)
            s += __shfl_xor(s, off, 64);
        if (lane == 0) s_pooled[f] = s * (1.0 / DD);
    }
    __syncthreads();

    // ---- Stage 2: h[r] = relu(dot(pooled, w1[r,:]) + b1[r])   (f64 exact, BIT-FROZEN)
    if (tid < RR) {
        double acc = (double)b1[tid];
        const float* wr = w1 + tid * FF;
        #pragma unroll
        for (int f = 0; f < FF; ++f) acc += s_pooled[f] * (double)wr[f];
        s_h[tid] = acc > 0.0 ? acc : 0.0;
    }
    __syncthreads();

    // ---- Stage 3: z[f] = dot(h, w2[f,:]) + b2[f]   (f64 exact, BIT-FROZEN)
    if (tid < FF) {
        double acc = (double)b2[tid];
        const float* wf = w2 + tid * RR;
        #pragma unroll
        for (int r = 0; r < RR; ++r) acc += s_h[r] * (double)wf[r];
        s_z[tid] = acc;
    }
    __syncthreads();

    // ---- Stage 4: rank on the np-style THREE-ROUNDING sigmoid chain
    // (BIT-FROZEN): e = f32(exp(-z)); den = f32(1+e); w = f32(1/den).
    // rank = #{j : w_j > w || (w_j == w && j < lane)}  (== descending sort,
    // ties -> lower index). Publish rank for ALL rows.
    if (wave == 0) {
        float e   = (float)exp(-s_z[lane]);   // f64 exp -> f32 round
        float den = 1.0f + e;                 // f32 round
        float v   = 1.0f / den;               // f32 round
        s_w[lane] = v;
        int rank = 0;
        #pragma unroll
        for (int j = 0; j < FF; ++j) {
            float wj = s_w[j];                // uniform broadcast, conflict-free
            rank += (wj > v || (wj == v && j < lane)) ? 1 : 0;
        }
        s_rank[lane] = rank;
    }
    __syncthreads();

    // ---- Stage 5: store selected rows straight from registers.
    // Wave-uniform branch; static register indices (no scratch);
    // perfectly coalesced 1KiB nontemporal store pairs.
    float* ob = out + (size_t)b * KK * DD;
    #pragma unroll
    for (int i = 0; i < 16; ++i) {
        const int f = wave + (i << 2);
        const int rk = s_rank[f];
        if (rk < KK) {
            f32x4* dst = (f32x4*)(ob + rk * DD);
            __builtin_nontemporal_store(v0[i], dst + lane);
            __builtin_nontemporal_store(v1[i], dst + lane + 64);
        }
    }
}

extern "C" void kernel_launch(void* const* d_in, const int* in_sizes, int n_in,
                              void* d_out, int out_size, void* d_ws, size_t ws_size,
                              hipStream_t stream) {
    const float* x  = (const float*)d_in[0];
    const float* w1 = (const float*)d_in[1];
    const float* b1 = (const float*)d_in[2];
    const float* w2 = (const float*)d_in[3];
    const float* b2 = (const float*)d_in[4];
    float* out = (float*)d_out;

    ca1d_fused<<<BB, 256, 0, stream>>>(x, w1, b1, w2, b2, out);
}